// Round 6
// baseline (167.841 us; speedup 1.0000x reference)
//
#include <hip/hip_runtime.h>

#define N_PTS 8192
#define BATCH 2
#define KNN 8
#define NSLAB 128                  // 64-point slabs of the sorted arrays
#define CELLS 512                  // 8x8x8 Morton grid
#define NBLK_C 1024                // chamfer: 4 combos x 256 row-blocks (32 rows)
#define NBLK_S 2048                // smooth: 2 batches x 1024 groups (8 pts, 2/wave)
#define NBLOCKS (NBLK_C + NBLK_S)  // role-interleaved by bx%3 (1 C : 2 S)

// workspace layout (float4 units):
//  [0 .. 6*8192)        sorted packed arrays: float4(x,y,z,|p|^2)
//    arr 0,1: pc2[b] | arr 2,3: pc1[b]+flow[b] (warped) | arr 4,5: pc1[b]
//  [WS_BB0 ..) bbox min per [arr][slab]; [WS_BB1 ..) bbox max
//  oidx (u32[2][8192], sorted->orig index for pc1 arrays) after WS_OIDX
#define ARR_PC2  0
#define ARR_WARP 2
#define ARR_PC1  4
#define WS_BB0   49152
#define WS_BB1   49920
#define WS_OIDX  50688             // float4 index where u32 oidx area starts

// ---------------- helpers ----------------
__device__ __forceinline__ void ce(unsigned &x, unsigned &y) {
    unsigned lo = min(x, y), hi = max(x, y); x = lo; y = hi;
}

__device__ __forceinline__ void insert4(unsigned o[4], unsigned key) {
    unsigned n0 = min(o[0], key);
    unsigned n1 = max(o[0], min(o[1], key));
    unsigned n2 = max(o[1], min(o[2], key));
    unsigned n3 = max(o[2], min(o[3], key));
    o[0]=n0; o[1]=n1; o[2]=n2; o[3]=n3;
}

__device__ __forceinline__ void merge_stage8(unsigned m[8], int d) {
    unsigned p[8], c[8];
    #pragma unroll
    for (int k = 0; k < 8; ++k) p[k] = (unsigned)__shfl_xor((int)m[k], d, 64);
    #pragma unroll
    for (int k = 0; k < 8; ++k) c[k] = min(m[k], p[7-k]);
    ce(c[0],c[4]); ce(c[1],c[5]); ce(c[2],c[6]); ce(c[3],c[7]);
    ce(c[0],c[2]); ce(c[1],c[3]); ce(c[4],c[6]); ce(c[5],c[7]);
    ce(c[0],c[1]); ce(c[2],c[3]); ce(c[4],c[5]); ce(c[6],c[7]);
    #pragma unroll
    for (int k = 0; k < 8; ++k) m[k] = c[k];
}

__device__ __forceinline__ void merge64(unsigned m[8]) {
    merge_stage8(m, 1); merge_stage8(m, 2); merge_stage8(m, 4);
    merge_stage8(m, 8); merge_stage8(m, 16); merge_stage8(m, 32);
}

// ordered-uint encode/decode for float atomicMin/Max on LDS
__device__ __forceinline__ unsigned f2o(float f) {
    unsigned u = __float_as_uint(f);
    return (u & 0x80000000u) ? ~u : (u | 0x80000000u);
}
__device__ __forceinline__ float o2f(unsigned u) {
    return __uint_as_float((u & 0x80000000u) ? (u ^ 0x80000000u) : ~u);
}

__device__ __forceinline__ unsigned spread3(unsigned v) {
    return ((v & 4u) << 4) | ((v & 2u) << 2) | (v & 1u);   // bits -> 6,3,0
}
__device__ __forceinline__ int cellof(float x, float y, float z) {
    int ix = min(7, max(0, (int)((x + 3.0f) * 1.3333333f)));
    int iy = min(7, max(0, (int)((y + 3.0f) * 1.3333333f)));
    int iz = min(7, max(0, (int)((z + 3.0f) * 1.3333333f)));
    return (int)((spread3((unsigned)ix) << 2) | (spread3((unsigned)iy) << 1)
                 | spread3((unsigned)iz));                  // 9-bit Morton
}

// squared distance point -> AABB (0 inside); exact lower bound for any point in slab
__device__ __forceinline__ float boxd2(const float4 bn, const float4 bx,
                                       float x, float y, float z) {
    float tx = fmaxf(fmaxf(bn.x - x, x - bx.x), 0.0f);     // v_max3
    float ty = fmaxf(fmaxf(bn.y - y, y - bx.y), 0.0f);
    float tz = fmaxf(fmaxf(bn.z - z, z - bx.z), 0.0f);
    return fmaf(tx, tx, fmaf(ty, ty, tz * tz));
}

// ---------------- pack+sort: 6 blocks, one array each ----------------
// LDS counting-sort by Morton cell + per-output-slab AABB via LDS atomics.
__global__ __launch_bounds__(512) void pack_sort_kernel(
        const float* __restrict__ pc1, const float* __restrict__ pc2,
        const float* __restrict__ flow, float4* __restrict__ ws,
        unsigned* __restrict__ oidx) {
    __shared__ unsigned hist[CELLS];
    __shared__ unsigned offs[CELLS];
    __shared__ unsigned bbn[NSLAB * 3], bbx[NSLAB * 3];
    const int arr = blockIdx.x, t = threadIdx.x;
    const int bbatch = arr & 1;
    const bool warped = (arr >= 2 && arr < 4);
    const float* A = (arr < 2) ? pc2 : pc1;
    const size_t base = (size_t)bbatch * N_PTS * 3;

    for (int i = t; i < CELLS; i += 512) hist[i] = 0u;
    for (int i = t; i < NSLAB * 3; i += 512) { bbn[i] = 0xFFFFFFFFu; bbx[i] = 0u; }
    __syncthreads();

    int cid[16];
    #pragma unroll
    for (int k = 0; k < 16; ++k) {
        int i = t * 16 + k;
        float x = A[base + i*3+0], y = A[base + i*3+1], z = A[base + i*3+2];
        if (warped) { x += flow[base+i*3+0]; y += flow[base+i*3+1]; z += flow[base+i*3+2]; }
        cid[k] = cellof(x, y, z);
        atomicAdd(&hist[cid[k]], 1u);
    }
    __syncthreads();

    // exclusive scan of 512 bins by wave 0 (8 bins/lane + lane butterfly)
    if (t < 64) {
        unsigned loc[8], s = 0;
        #pragma unroll
        for (int q = 0; q < 8; ++q) { loc[q] = s; s += hist[t*8 + q]; }
        unsigned run = s;
        #pragma unroll
        for (int d = 1; d < 64; d <<= 1) {
            unsigned v = (unsigned)__shfl_up((int)run, d, 64);
            if (t >= d) run += v;
        }
        unsigned bse = run - s;
        #pragma unroll
        for (int q = 0; q < 8; ++q) offs[t*8 + q] = bse + loc[q];
    }
    __syncthreads();

    #pragma unroll
    for (int k = 0; k < 16; ++k) {
        int i = t * 16 + k;
        float x = A[base + i*3+0], y = A[base + i*3+1], z = A[base + i*3+2];
        if (warped) { x += flow[base+i*3+0]; y += flow[base+i*3+1]; z += flow[base+i*3+2]; }
        unsigned pos = atomicAdd(&offs[cid[k]], 1u);
        ws[(size_t)arr * N_PTS + pos] = make_float4(x, y, z, fmaf(x, x, fmaf(y, y, z*z)));
        if (arr >= 4) oidx[(size_t)(arr - 4) * N_PTS + pos] = (unsigned)i;
        int s = (int)(pos >> 6);
        atomicMin(&bbn[s*3+0], f2o(x)); atomicMax(&bbx[s*3+0], f2o(x));
        atomicMin(&bbn[s*3+1], f2o(y)); atomicMax(&bbx[s*3+1], f2o(y));
        atomicMin(&bbn[s*3+2], f2o(z)); atomicMax(&bbx[s*3+2], f2o(z));
    }
    __syncthreads();

    for (int s = t; s < NSLAB; s += 512) {
        ws[WS_BB0 + (size_t)arr * NSLAB + s] =
            make_float4(o2f(bbn[s*3+0]), o2f(bbn[s*3+1]), o2f(bbn[s*3+2]), 0.0f);
        ws[WS_BB1 + (size_t)arr * NSLAB + s] =
            make_float4(o2f(bbx[s*3+0]), o2f(bbx[s*3+1]), o2f(bbx[s*3+2]), 0.0f);
    }
}

// ---------------- mega: slab-pruned exact scans, role-interleaved ----------------
// R5 post-mortem: kernel is VALU-WORK-bound (88% busy, all micro-levers <=5%).
// R6 attacks the work itself: Morton-sorted candidates + per-slab AABB lower
// bounds. Skip a slab only when lb > proven upper bound -> exact result,
// ~5-10x fewer distance evals. All control flow wave-uniform (ballot masks,
// uniform __ffsll loops). Seed slabs tracked as bitmasks -> dedupe free, and
// pass-2 masks clear them -> no candidate scanned twice (top-8 exactness).
__global__ __launch_bounds__(256, 4) void mega_kernel(
        const float4* __restrict__ ws, const float* __restrict__ flow,
        const unsigned* __restrict__ oidx, float* __restrict__ out) {
    __shared__ float psum[4];
    const int tid = threadIdx.x, bx = blockIdx.x;
    const int lane = tid & 63, wv = tid >> 6;
    const int ri = bx / 3, role = bx % 3;

    if (role == 2) {
        // ============ role C: chamfer, 8 sorted rows/wave, slab-pruned min ============
        const int z = ri >> 8, bb = z & 1, dir = z >> 1;
        const int cb = ri & 255;
        const int ca = (dir == 0 ? ARR_PC2 : ARR_WARP) + bb;
        const int ra = (dir == 0 ? ARR_WARP : ARR_PC2) + bb;
        const float4* rows = ws + (size_t)ra * N_PTS;
        const float4* cand = ws + (size_t)ca * N_PTS;
        const float4* bmn = ws + WS_BB0 + (size_t)ca * NSLAB;
        const float4* bmx = ws + WS_BB1 + (size_t)ca * NSLAB;
        const int rbase = cb * 32 + wv * 8;   // wave-uniform 8 consecutive sorted rows

        float rx[8], ry[8], rz[8], bmin[8];
        #pragma unroll
        for (int k = 0; k < 8; ++k) {
            float4 q = rows[rbase + k];
            rx[k] = q.x; ry[k] = q.y; rz[k] = q.z;
            bmin[k] = __builtin_inff();
        }
        // lane owns slabs {lane, lane+64}: lb per (slab,row) + per-row argmin seed
        float4 bn0 = bmn[lane], bx0 = bmx[lane];
        float4 bn1 = bmn[lane + 64], bx1 = bmx[lane + 64];
        float lb0[8], lb1[8];
        unsigned long long sm0 = 0ull, sm1 = 0ull;
        #pragma unroll
        for (int k = 0; k < 8; ++k) {
            lb0[k] = boxd2(bn0, bx0, rx[k], ry[k], rz[k]);
            lb1[k] = boxd2(bn1, bx1, rx[k], ry[k], rz[k]);
            // argmin-lb slab: key = lb bits (trunc low 7) | slab id; butterfly min
            unsigned k0 = (__float_as_uint(lb0[k]) & 0xFFFFFF80u) | (unsigned)lane;
            unsigned k1 = (__float_as_uint(lb1[k]) & 0xFFFFFF80u) | (unsigned)(lane + 64);
            unsigned kk = min(k0, k1);
            #pragma unroll
            for (int d = 1; d < 64; d <<= 1)
                kk = min(kk, (unsigned)__shfl_xor((int)kk, d, 64));
            unsigned s = kk & 127u;
            if (s < 64) sm0 |= 1ull << s; else sm1 |= 1ull << (s - 64);
        }
        auto scan_slab = [&](int s) {
            float4 c = cand[s * 64 + lane];
            #pragma unroll
            for (int k = 0; k < 8; ++k) {
                float dx = rx[k] - c.x, dy = ry[k] - c.y, dz = rz[k] - c.z;
                bmin[k] = fminf(bmin[k], fmaf(dx, dx, fmaf(dy, dy, dz * dz)));
            }
        };
        { unsigned long long m = sm0; while (m) { int s = __ffsll((unsigned long long)m) - 1; m &= m - 1; scan_slab(s); } }
        { unsigned long long m = sm1; while (m) { int s = __ffsll((unsigned long long)m) - 1; m &= m - 1; scan_slab(s + 64); } }
        // wave ub per row (real distances) -> per-lane slab pass flags
        bool p0 = false, p1 = false;
        #pragma unroll
        for (int k = 0; k < 8; ++k) {
            float u = bmin[k];
            #pragma unroll
            for (int d = 1; d < 64; d <<= 1)
                u = fminf(u, __shfl_xor(u, d, 64));
            p0 |= (lb0[k] < u);
            p1 |= (lb1[k] < u);
        }
        unsigned long long q0 = __ballot(p0) & ~sm0;
        unsigned long long q1 = __ballot(p1) & ~sm1;
        while (q0) { int s = __ffsll(q0) - 1; q0 &= q0 - 1; scan_slab(s); }
        while (q1) { int s = __ffsll(q1) - 1; q1 &= q1 - 1; scan_slab(s + 64); }
        // reduce: full-wave min per row, lane0 sums sqrt
        #pragma unroll
        for (int k = 0; k < 8; ++k) {
            #pragma unroll
            for (int d = 1; d < 64; d <<= 1)
                bmin[k] = fminf(bmin[k], __shfl_xor(bmin[k], d, 64));
        }
        if (lane == 0) {
            float val = 0.0f;
            #pragma unroll
            for (int k = 0; k < 8; ++k) val += sqrtf(fmaxf(bmin[k], 0.0f));
            psum[wv] = val;
        }
        __syncthreads();
        if (tid == 0) {
            float ch = psum[0] + psum[1] + psum[2] + psum[3];
            atomicAdd(out, ch * (1.0f / (float)(BATCH * N_PTS)));
        }
    } else {
        // ============ role S: smooth, 2 sorted rows/wave, slab-pruned top-8 ============
        const int sbx = ri * 2 + role;          // [0, 2048)
        const int b = sbx >> 10, sx = sbx & 1023;
        const int i0w = sx * 8 + wv * 2;        // sorted positions i0w, i0w+1
        const float4* cand = ws + (size_t)(ARR_PC1 + b) * N_PTS;
        const float4* bmn = ws + WS_BB0 + (size_t)(ARR_PC1 + b) * NSLAB;
        const float4* bmx = ws + WS_BB1 + (size_t)(ARR_PC1 + b) * NSLAB;
        const unsigned* OI = oidx + (size_t)b * N_PTS;
        const float* F = flow + (size_t)b * N_PTS * 3;

        float rx[2], ry[2], rz[2], thrf[2];
        unsigned thr[2], o[2][4];
        #pragma unroll
        for (int r = 0; r < 2; ++r) {
            float4 q = cand[i0w + r];           // wave-uniform
            rx[r] = q.x; ry[r] = q.y; rz[r] = q.z;
            thr[r] = 0xFFFFFFFFu;
            #pragma unroll
            for (int k = 0; k < 4; ++k) o[r][k] = 0xFFFFFFFFu;
        }
        float4 bn0 = bmn[lane], bx0 = bmx[lane];
        float4 bn1 = bmn[lane + 64], bx1 = bmx[lane + 64];
        float lb0[2], lb1[2];
        unsigned long long sm0 = 0ull, sm1 = 0ull;
        { int so = i0w >> 6;                     // own slab (both rows: i0w even)
          if (so < 64) sm0 |= 1ull << so; else sm1 |= 1ull << (so - 64); }
        #pragma unroll
        for (int r = 0; r < 2; ++r) {
            lb0[r] = boxd2(bn0, bx0, rx[r], ry[r], rz[r]);
            lb1[r] = boxd2(bn1, bx1, rx[r], ry[r], rz[r]);
            unsigned k0 = (__float_as_uint(lb0[r]) & 0xFFFFFF80u) | (unsigned)lane;
            unsigned k1 = (__float_as_uint(lb1[r]) & 0xFFFFFF80u) | (unsigned)(lane + 64);
            unsigned kk = min(k0, k1);
            #pragma unroll
            for (int d = 1; d < 64; d <<= 1)
                kk = min(kk, (unsigned)__shfl_xor((int)kk, d, 64));
            unsigned s = kk & 127u;
            if (s < 64) sm0 |= 1ull << s; else sm1 |= 1ull << (s - 64);
        }
        auto scan_slab = [&](int s) {
            float4 c = cand[s * 64 + lane];
            int j = s * 64 + lane;
            #pragma unroll
            for (int r = 0; r < 2; ++r) {
                float dx = rx[r] - c.x, dy = ry[r] - c.y, dz = rz[r] - c.z;
                float d2 = fmaf(dx, dx, fmaf(dy, dy, dz * dz));
                unsigned key = (__float_as_uint(d2) & 0xFFFFE000u) | (unsigned)j;
                key = (j == i0w + r) ? 0xFFFFFFFFu : key;   // self-exclusion
                insert4(o[r], key);
            }
        };
        { unsigned long long m = sm0; while (m) { int s = __ffsll(m) - 1; m &= m - 1; scan_slab(s); } }
        { unsigned long long m = sm1; while (m) { int s = __ffsll(m) - 1; m &= m - 1; scan_slab(s + 64); } }
        // tight thr from seed: per-32-half true top-4 butterfly; bound = max of
        // halves' 4th keys = 8 distinct real keys >= true 8th (halves have
        // disjoint j). thr_up strictly exceeds d2 of any key <= thr.
        #pragma unroll
        for (int r = 0; r < 2; ++r) {
            unsigned m0 = o[r][0], m1 = o[r][1], m2 = o[r][2], m3 = o[r][3];
            #pragma unroll
            for (int d = 1; d <= 16; d <<= 1) {
                unsigned q0 = (unsigned)__shfl_xor((int)m0, d, 64);
                unsigned q1 = (unsigned)__shfl_xor((int)m1, d, 64);
                unsigned q2 = (unsigned)__shfl_xor((int)m2, d, 64);
                unsigned q3 = (unsigned)__shfl_xor((int)m3, d, 64);
                unsigned c0 = min(m0, q3), c1 = min(m1, q2);
                unsigned c2 = min(m2, q1), c3 = min(m3, q0);
                ce(c0, c2); ce(c1, c3); ce(c0, c1); ce(c2, c3);
                m0 = c0; m1 = c1; m2 = c2; m3 = c3;
            }
            unsigned bound = max(m3, (unsigned)__shfl_xor((int)m3, 32, 64));
            thr[r] = min(thr[r], bound);
            thrf[r] = __uint_as_float((thr[r] & 0xFFFFE000u) + 0x4000u);
        }
        bool p0 = (lb0[0] < thrf[0]) | (lb0[1] < thrf[1]);
        bool p1 = (lb1[0] < thrf[0]) | (lb1[1] < thrf[1]);
        unsigned long long q0 = __ballot(p0) & ~sm0;
        unsigned long long q1 = __ballot(p1) & ~sm1;
        while (q0) { int s = __ffsll(q0) - 1; q0 &= q0 - 1; scan_slab(s); }
        while (q1) { int s = __ffsll(q1) - 1; q1 &= q1 - 1; scan_slab(s + 64); }

        // final per-point top-8 + epilogue (sel over 16 lanes, dup x4 -> /4)
        const int sel = lane & 15;
        const int pr = sel >> 3, kk = sel & 7;
        unsigned mykey = 0xFFFFFFFFu;
        #pragma unroll
        for (int r = 0; r < 2; ++r) {
            unsigned m[8] = {o[r][0], o[r][1], o[r][2], o[r][3],
                             0xFFFFFFFFu, 0xFFFFFFFFu, 0xFFFFFFFFu, 0xFFFFFFFFu};
            merge64(m);
            if (pr == r) {
                unsigned k2 = m[0];
                #pragma unroll
                for (int t2 = 1; t2 < 8; ++t2) k2 = (kk == t2) ? m[t2] : k2;
                mykey = k2;
            }
        }
        const int isrt = i0w + pr;
        const int io = (int)OI[isrt];                 // sorted -> original index
        const int j  = (int)(mykey & (N_PTS - 1));
        const int jo = (int)OI[j];
        float dx = F[io*3+0] - F[jo*3+0];
        float dy = F[io*3+1] - F[jo*3+1];
        float dz = F[io*3+2] - F[jo*3+2];
        float sv = sqrtf(fmaf(dx, dx, fmaf(dy, dy, dz * dz)));
        #pragma unroll
        for (int d = 1; d < 64; d <<= 1) sv += __shfl_xor(sv, d, 64);
        if (lane == 0) psum[wv] = sv;
        __syncthreads();

        if (tid == 0) {
            float sm = psum[0] + psum[1] + psum[2] + psum[3];
            // smooth: W=0.5, /4 lane dup -> 0.125
            atomicAdd(out, sm * (0.125f / ((float)BATCH * N_PTS * KNN)));
        }
    }
}

extern "C" void kernel_launch(void* const* d_in, const int* in_sizes, int n_in,
                              void* d_out, int out_size, void* d_ws, size_t ws_size,
                              hipStream_t stream) {
    const float* pc1  = (const float*)d_in[0];
    const float* pc2  = (const float*)d_in[1];
    const float* flow = (const float*)d_in[2];
    float* out = (float*)d_out;
    float4* ws4 = (float4*)d_ws;                      // needs ~877 KiB
    unsigned* oidx = (unsigned*)(ws4 + WS_OIDX);

    pack_sort_kernel<<<dim3(6), 512, 0, stream>>>(pc1, pc2, flow, ws4, oidx);
    mega_kernel<<<dim3(NBLOCKS), 256, 0, stream>>>(ws4, flow, oidx, out);
}